// Round 11
// baseline (106.941 us; speedup 1.0000x reference)
//
#include <hip/hip_runtime.h>

// PointNet 3-NN feature interpolation, v11: wave-cooperative scan, no LDS.
// pack_points: xyz1 -> packed {2x,2y,2z,norm} float4 (1 MB, L2-resident).
// knn3_tau   : wave = 4 queries; lanes partition pts 0..1023; value-only
//              running top-3 + d-only butterfly -> tau[q] (exact bound).
// knn3_wave  : wave = 4 queries; lanes partition ALL N pts; filter d<=tau;
//              lexicographic (d,idx) top-3 + butterfly merge; weights inline.
// interp     : per-(b,d) row staged in LDS, gather+weighted-sum.

constexpr int QW   = 4;          // queries per wave
constexpr int TAUP = 1024;       // tau sample points (first TAUP)
constexpr float DINF = 3.4e38f;
constexpr int   ISENT = 0x7fffffff;

// lexicographic (d, idx) insert, branch-guarded (caller may pre-filter)
__device__ __forceinline__ void ins_lex(float& d0, float& d1, float& d2,
                                        int& i0, int& i1, int& i2,
                                        float d, int n) {
    bool l2 = (d < d2) || (d == d2 && n < i2);
    if (l2) {
        bool l1 = (d < d1) || (d == d1 && n < i1);
        bool l0 = (d < d0) || (d == d0 && n < i0);
        d2 = l1 ? d1 : d;  i2 = l1 ? i1 : n;
        d1 = l0 ? d0 : (l1 ? d : d1);
        i1 = l0 ? i0 : (l1 ? n : i1);
        d0 = l0 ? d  : d0; i0 = l0 ? n : i0;
    }
}

// branchless lexicographic insert (for the butterfly merge)
__device__ __forceinline__ void ins_lex_nb(float& d0, float& d1, float& d2,
                                           int& i0, int& i1, int& i2,
                                           float d, int n) {
    bool l2 = (d < d2) || (d == d2 && n < i2);
    bool l1 = (d < d1) || (d == d1 && n < i1);
    bool l0 = (d < d0) || (d == d0 && n < i0);
    float nd2 = l1 ? d1 : (l2 ? d : d2);
    int   ni2 = l1 ? i1 : (l2 ? n : i2);
    float nd1 = l0 ? d0 : (l1 ? d : d1);
    int   ni1 = l0 ? i0 : (l1 ? n : i1);
    d0 = l0 ? d : d0;  i0 = l0 ? n : i0;
    d1 = nd1; d2 = nd2; i1 = ni1; i2 = ni2;
}

// value-only top-3 insert
__device__ __forceinline__ void ins_v(float& d0, float& d1, float& d2, float d) {
    bool c0 = d < d0, c1 = d < d1, c2 = d < d2;
    float n2 = c1 ? d1 : (c2 ? d : d2);
    float n1 = c0 ? d0 : (c1 ? d : d1);
    d0 = c0 ? d : d0; d1 = n1; d2 = n2;
}

// pk[b*N+n] = {2x, 2y, 2z, (x*x + y*y) + z*z}. 2x exact (pow2 scale);
// (qx*2x + qy*2y) + qz*2z rounds bit-identically to 2*((qx*x+qy*y)+qz*z).
__global__ __launch_bounds__(256)
void pack_points(const float* __restrict__ xyz1, float4* __restrict__ pk,
                 int B, int N)
{
#pragma clang fp contract(off)
    int t = blockIdx.x * 256 + threadIdx.x;
    if (t >= B * N) return;
    int b = t / N, n = t - b * N;
    const float* __restrict__ bx = xyz1 + (size_t)b * 3 * N;
    float x = bx[n], y = bx[N + n], z = bx[2 * N + n];
    pk[t] = make_float4(x + x, y + y, z + z, (x * x + y * y) + z * z);
}

__global__ __launch_bounds__(256)
void knn3_tau(const float4* __restrict__ pk, const float* __restrict__ xyz2,
              int B, int N, int S, float* __restrict__ tau)
{
#pragma clang fp contract(off)
    const int lane = threadIdx.x & 63;
    const int wid  = (blockIdx.x * 256 + threadIdx.x) >> 6;
    const int qb   = wid * QW;
    const int b    = qb / S;                 // QW | S -> wave-uniform
    const int sb   = qb - b * S;

    const float* __restrict__ q2p = xyz2 + (size_t)b * 3 * S;
    float qx[QW], qy[QW], qz[QW], qs[QW];
#pragma unroll
    for (int j = 0; j < QW; ++j) {           // wave-uniform addrs -> s_load
        qx[j] = q2p[sb + j];
        qy[j] = q2p[S + sb + j];
        qz[j] = q2p[2 * S + sb + j];
        qs[j] = (qx[j] * qx[j] + qy[j] * qy[j]) + qz[j] * qz[j];
    }

    const float4* __restrict__ pb = pk + (size_t)b * N;
    float d0[QW], d1[QW], d2[QW];
#pragma unroll
    for (int j = 0; j < QW; ++j) { d0[j] = d1[j] = d2[j] = DINF; }

    for (int i = 0; i < TAUP / 64; ++i) {
        float4 p = pb[lane + 64 * i];
#pragma unroll
        for (int j = 0; j < QW; ++j) {
            float dot2 = (qx[j] * p.x + qy[j] * p.y) + qz[j] * p.z;
            float d    = (qs[j] + p.w) - dot2;
            ins_v(d0[j], d1[j], d2[j], d);
        }
    }
    // d-only butterfly: every lane ends with the global top-3 values
#pragma unroll
    for (int m = 32; m >= 1; m >>= 1) {
#pragma unroll
        for (int j = 0; j < QW; ++j) {
            float a0 = __shfl_xor(d0[j], m);
            float a1 = __shfl_xor(d1[j], m);
            float a2 = __shfl_xor(d2[j], m);
            ins_v(d0[j], d1[j], d2[j], a0);
            ins_v(d0[j], d1[j], d2[j], a1);
            ins_v(d0[j], d1[j], d2[j], a2);
        }
    }
#pragma unroll
    for (int j = 0; j < QW; ++j)
        if (lane == j) tau[qb + j] = d2[j];
}

__global__ __launch_bounds__(256)
void knn3_wave(const float4* __restrict__ pk, const float* __restrict__ xyz2,
               const float* __restrict__ tau, int B, int N, int S,
               int* __restrict__ idx0, int* __restrict__ idx1,
               int* __restrict__ idx2,
               float* __restrict__ w0, float* __restrict__ w1,
               float* __restrict__ w2)
{
#pragma clang fp contract(off)
    const int lane = threadIdx.x & 63;
    const int wid  = (blockIdx.x * 256 + threadIdx.x) >> 6;
    const int qb   = wid * QW;
    const int b    = qb / S;                 // QW | S -> wave-uniform
    const int sb   = qb - b * S;

    const float* __restrict__ q2p = xyz2 + (size_t)b * 3 * S;
    float qx[QW], qy[QW], qz[QW], qs[QW], tt[QW];
#pragma unroll
    for (int j = 0; j < QW; ++j) {           // wave-uniform addrs -> s_load
        qx[j] = q2p[sb + j];
        qy[j] = q2p[S + sb + j];
        qz[j] = q2p[2 * S + sb + j];
        qs[j] = (qx[j] * qx[j] + qy[j] * qy[j]) + qz[j] * qz[j];
        tt[j] = tau[qb + j];
    }

    const float4* __restrict__ pb = pk + (size_t)b * N;
    float d0[QW], d1[QW], d2[QW];
    int   i0[QW], i1[QW], i2[QW];
#pragma unroll
    for (int j = 0; j < QW; ++j) {
        d0[j] = d1[j] = d2[j] = DINF;
        i0[j] = i1[j] = i2[j] = ISENT;
    }

    const int NIT = N / 64;
    float4 cur = pb[lane];
    for (int i = 0; i < NIT - 1; ++i) {
        float4 nxt = pb[lane + 64 * (i + 1)];   // prefetch next iteration
        const int n = lane + 64 * i;
#pragma unroll
        for (int j = 0; j < QW; ++j) {
            float dot2 = (qx[j] * cur.x + qy[j] * cur.y) + qz[j] * cur.z;
            float d    = (qs[j] + cur.w) - dot2;
            if (__builtin_expect(d <= tt[j], 0))   // tau >= global d2: exact
                ins_lex(d0[j], d1[j], d2[j], i0[j], i1[j], i2[j], d, n);
        }
        cur = nxt;
    }
    {   // last iteration
        const int n = lane + 64 * (NIT - 1);
#pragma unroll
        for (int j = 0; j < QW; ++j) {
            float dot2 = (qx[j] * cur.x + qy[j] * cur.y) + qz[j] * cur.z;
            float d    = (qs[j] + cur.w) - dot2;
            if (__builtin_expect(d <= tt[j], 0))
                ins_lex(d0[j], d1[j], d2[j], i0[j], i1[j], i2[j], d, n);
        }
    }

    // lexicographic butterfly: all lanes converge to the exact top-3
#pragma unroll
    for (int m = 32; m >= 1; m >>= 1) {
#pragma unroll
        for (int j = 0; j < QW; ++j) {
            float a0 = __shfl_xor(d0[j], m);
            float a1 = __shfl_xor(d1[j], m);
            float a2 = __shfl_xor(d2[j], m);
            int   b0 = __shfl_xor(i0[j], m);
            int   b1 = __shfl_xor(i1[j], m);
            int   b2 = __shfl_xor(i2[j], m);
            ins_lex_nb(d0[j], d1[j], d2[j], i0[j], i1[j], i2[j], a0, b0);
            ins_lex_nb(d0[j], d1[j], d2[j], i0[j], i1[j], i2[j], a1, b1);
            ins_lex_nb(d0[j], d1[j], d2[j], i0[j], i1[j], i2[j], a2, b2);
        }
    }

#pragma unroll
    for (int j = 0; j < QW; ++j) {
        if (lane == j) {                      // static j: no dynamic indexing
            const int q = qb + j;
            float r0 = 1.0f / (d0[j] + 1e-8f);
            float r1 = 1.0f / (d1[j] + 1e-8f);
            float r2 = 1.0f / (d2[j] + 1e-8f);
            float sum = (r0 + r1) + r2;       // np sum order
            idx0[q] = i0[j]; idx1[q] = i1[j]; idx2[q] = i2[j];
            w0[q] = r0 / sum; w1[q] = r1 / sum; w2[q] = r2 / sum;
        }
    }
}

__global__ __launch_bounds__(256)
void interp_kernel(const float* __restrict__ points1,
                   const int* __restrict__ idx0, const int* __restrict__ idx1,
                   const int* __restrict__ idx2,
                   const float* __restrict__ w0, const float* __restrict__ w1,
                   const float* __restrict__ w2,
                   float* __restrict__ out, int N, int S, int D)
{
#pragma clang fp contract(off)
    __shared__ float row[8192];
    const int bd = blockIdx.x;
    const int b  = bd / D;
    const float* __restrict__ src = points1 + (size_t)bd * N;

    for (int i = threadIdx.x * 4; i < N; i += blockDim.x * 4) {
        *reinterpret_cast<float4*>(&row[i]) =
            *reinterpret_cast<const float4*>(src + i);
    }
    __syncthreads();

    float* __restrict__ dst = out + (size_t)bd * S;
    const int qb = b * S;
    for (int s = threadIdx.x; s < S; s += blockDim.x) {
        int q = qb + s;
        float a = row[idx0[q]] * w0[q];
        float c = row[idx1[q]] * w1[q];
        float e = row[idx2[q]] * w2[q];
        dst[s] = (a + c) + e;                 // np sum order
    }
}

extern "C" void kernel_launch(void* const* d_in, const int* in_sizes, int n_in,
                              void* d_out, int out_size, void* d_ws, size_t ws_size,
                              hipStream_t stream) {
    const float* xyz1    = (const float*)d_in[0];
    const float* xyz2    = (const float*)d_in[1];
    const float* points1 = (const float*)d_in[2];
    float* out = (float*)d_out;

    const int B = 8;
    const int N = in_sizes[0] / (3 * B);
    const int S = in_sizes[1] / (3 * B);
    const int D = in_sizes[2] / (B * N);
    const int BS = B * S;

    // ws: pk (16B aligned) | idx0..2 | w0..2 | tau   (~1.5 MB total)
    float4* pk   = (float4*)d_ws;
    int*    idx0 = (int*)(pk + (size_t)B * N);
    int*    idx1 = idx0 + BS;
    int*    idx2 = idx1 + BS;
    float*  w0   = (float*)(idx2 + BS);
    float*  w1   = w0 + BS;
    float*  w2   = w1 + BS;
    float*  tau  = w2 + BS;

    pack_points<<<(B * N + 255) / 256, 256, 0, stream>>>(xyz1, pk, B, N);

    const int nWave   = BS / QW;              // 4096 waves
    const int nBlocks = nWave / 4;            // 1024 blocks (4 waves each)
    knn3_tau<<<nBlocks, 256, 0, stream>>>(pk, xyz2, B, N, S, tau);

    knn3_wave<<<nBlocks, 256, 0, stream>>>(pk, xyz2, tau, B, N, S,
                                           idx0, idx1, idx2, w0, w1, w2);

    interp_kernel<<<B * D, 256, 0, stream>>>(points1, idx0, idx1, idx2,
                                             w0, w1, w2, out, N, S, D);
}